// Round 6
// baseline (72461.621 us; speedup 1.0000x reference)
//
#include <hip/hip_runtime.h>
#include <math.h>

// ESN reservoir, persistent kernel, round 6.
// h_t = tanh(x_t Win^T + h_{t-1} W^T); out_t = h_t Wout^T + b
//
// Round-5 diagnosis: VALUBusy 10% -> barrier polling contention: 255 blocks
// spinning system-scope loads on ONE line serialize at the coherence point
// (~25us observed-latency per step).
// Round-6: ONE change -> fan-in-16 TREE barrier, <=16 pollers per line:
//   arrive: block b stores flags[b] (group g's 16 flags share one 64B line)
//   agg g (block g*16) polls its children line (sole poller)
//          -> stores l1[g] (one line, 16 aggregator pollers)
//          -> polls full l1 line -> stores go2[g] (own 64B line)
//   children poll go2[g] (<=15 pollers). ~5 uncontended hops ~2us.
// Everything else identical to round 5 (L2-bypass h handoff, rotating-block
// projection overlapped with barrier wait, bounded spins -> never hangs).

#define RDIM   2048
#define BATCH  16
#define TSTEPS 2048
#define NIN    3
#define NOUT   3
#define NBLK   256
#define NTHR   512

#define HB_U32     ((BATCH * RDIM) / 2)     // h buffer in dwords (2 bf16/dword)
#define OFF_H0_U32 0
#define OFF_H1_U32 (HB_U32)
#define OFF_FLAGS  (2 * HB_U32)             // 256 dwords: group g at [g*16..+15]
#define OFF_L1     (OFF_FLAGS + 256)        // 16 dwords, one 64B line
#define OFF_GO2    (OFF_L1 + 16)            // 16 lines: go2[g] at [g*16]
#define WS_USED    (OFF_GO2 + 256)
#define SPIN_MAX   (1L << 20)

// CPol bits (LLVM SIDefines): GLC/SC0=1, SLC/NT=2, SCC/SC1=16
#define CPOL_SC0_SC1 0x11

__device__ __forceinline__ void load_lds16_coherent(const void* g, void* l) {
    __builtin_amdgcn_global_load_lds(
        (const __attribute__((address_space(1))) void*)g,
        (__attribute__((address_space(3))) void*)l, 16, 0, CPOL_SC0_SC1);
}

__device__ __forceinline__ unsigned sysld(const unsigned* p) {
    return __hip_atomic_load(p, __ATOMIC_RELAXED, __HIP_MEMORY_SCOPE_SYSTEM);
}
__device__ __forceinline__ void sysst(unsigned* p, unsigned v) {
    __hip_atomic_store(p, v, __ATOMIC_RELAXED, __HIP_MEMORY_SCOPE_SYSTEM);
}

__device__ __forceinline__ float bf16lo(unsigned u) {
    union { unsigned u; float f; } c; c.u = u << 16; return c.f;
}
__device__ __forceinline__ float bf16hi(unsigned u) {
    union { unsigned u; float f; } c; c.u = u & 0xffff0000u; return c.f;
}
__device__ __forceinline__ unsigned f2bf(float f) {
    union { float f; unsigned u; } c; c.f = f;
    unsigned r = c.u + 0x7fffu + ((c.u >> 16) & 1u);   // round-to-nearest-even
    return r >> 16;
}

extern "C" __global__ void __launch_bounds__(NTHR, 1) esn_persist(
    const float* __restrict__ W,       // [R,R]
    const float* __restrict__ Win,     // [R,3]
    const float* __restrict__ x,       // [B,T,3]
    const float* __restrict__ Wout,    // [3,R]
    const float* __restrict__ bout,    // [3]
    unsigned* hb0,                     // [B*R/2] packed bf16x2
    unsigned* hb1,
    unsigned* flags,                   // [256]
    unsigned* l1,                      // [16]
    unsigned* go2,                     // [256], go2[g*16] used
    float* __restrict__ out)           // [B,T,3]
{
    __shared__ unsigned short hs[BATCH * RDIM];  // 64 KB, intact all step
    __shared__ float red[8][544];                // reduce scratch
    __shared__ float hblk[8][16];                // block's 8 rows of h_new

    const int tid  = threadIdx.x;
    const int lane = tid & 63;
    const int w    = tid >> 6;                  // wave 0..7
    const int blk  = blockIdx.x;
    const int grp  = blk >> 4;                  // barrier group 0..15
    const int row0 = blk * 8;
    const int rbase = row0 + (w >> 1) * 2;      // 2 rows per wave
    const int bbase = (w & 1) * 8;              // 8 batches per wave

    const float4* W4 = (const float4*)W;

    for (int t = 0; t <= TSTEPS; ++t) {
        const unsigned* hprev = (t & 1) ? hb1 : hb0;
        unsigned*       hnext = (t & 1) ? hb0 : hb1;

        // ---- stage full h (64KB) -> LDS; L2-bypassing (sc0 sc1) ----
#pragma unroll
        for (int i = 0; i < 8; ++i) {
            const int base = i * 512 + w * 64;              // 16B granule idx
            load_lds16_coherent(hprev + (size_t)(base + lane) * 4,
                                hs + (size_t)base * 8);
        }
        __syncthreads();   // (#1) staging complete

        if (t < TSTEPS) {
            // ---- recurrence: acc[r][b] over lane's k-slice ----
            float acc[2][8];
#pragma unroll
            for (int r = 0; r < 2; ++r)
#pragma unroll
                for (int b = 0; b < 8; ++b) acc[r][b] = 0.f;

            const uint4* h16 = (const uint4*)hs;    // 8 bf16 per uint4
#pragma unroll
            for (int c = 0; c < 4; ++c) {
                const int g = c * 64 + lane;        // k = g*8 .. +8
                float4 wv[2][2];
#pragma unroll
                for (int r = 0; r < 2; ++r) {
                    const float4* Wp = W4 + (size_t)(rbase + r) * (RDIM / 4) + g * 2;
                    wv[r][0] = Wp[0];
                    wv[r][1] = Wp[1];
                }
#pragma unroll
                for (int b = 0; b < 8; ++b) {
                    uint4 q = h16[(bbase + b) * (RDIM / 8) + g];
                    float f0 = bf16lo(q.x), f1 = bf16hi(q.x);
                    float f2 = bf16lo(q.y), f3 = bf16hi(q.y);
                    float f4 = bf16lo(q.z), f5 = bf16hi(q.z);
                    float f6 = bf16lo(q.w), f7 = bf16hi(q.w);
#pragma unroll
                    for (int r = 0; r < 2; ++r) {
                        acc[r][b] += wv[r][0].x * f0 + wv[r][0].y * f1
                                   + wv[r][0].z * f2 + wv[r][0].w * f3
                                   + wv[r][1].x * f4 + wv[r][1].y * f5
                                   + wv[r][1].z * f6 + wv[r][1].w * f7;
                    }
                }
            }

            // ---- reduce 64 lanes -> 16 (r,b) sums per wave ----
            float v[16];
#pragma unroll
            for (int i = 0; i < 16; ++i) {
                float a = acc[i >> 3][i & 7];
                v[i] = a + __shfl_xor(a, 32, 64);
            }
            if (lane < 32) {
#pragma unroll
                for (int i = 0; i < 16; ++i)
                    red[w][lane * 17 + ((i + lane) & 15)] = v[i];
            }
            __syncthreads();   // (#2a) red ready
            if (lane < 16) {
                float s = 0.f;
#pragma unroll
                for (int l = 0; l < 32; ++l)
                    s += red[w][l * 17 + ((lane + l) & 15)];
                const int r   = lane >> 3;
                const int b   = lane & 7;
                const int row = rbase + r;
                const int bg  = bbase + b;
                float pre = s;
#pragma unroll
                for (int c = 0; c < NIN; ++c)
                    pre += Win[row * NIN + c] * x[((size_t)bg * TSTEPS + t) * NIN + c];
                hblk[(w >> 1) * 2 + r][bg] = tanhf(pre);
            }
            __syncthreads();   // (#2b) hblk complete

            // ---- write-through h_new strips: wave 0, 64 packed dwords ----
            if (w == 0) {
                const int bg = lane >> 2;          // batch 0..15
                const int d  = lane & 3;           // dword within 8-row strip
                unsigned lo = f2bf(hblk[2 * d][bg]);
                unsigned hi = f2bf(hblk[2 * d + 1][bg]);
                sysst(&hnext[bg * (RDIM / 2) + blk * 4 + d], lo | (hi << 16));
                __builtin_amdgcn_s_waitcnt(0);     // drain before flagging
            }
            __syncthreads();   // (#2c) all h stores globally visible

            if (tid == 0) sysst(&flags[blk], (unsigned)(t + 1));
        }

        // ---- projection of h_{t-1} (in hs) by rotating designated block ----
        // After flag-arrival: overlaps other blocks' barrier wait.
        if (t > 0 && blk == ((t - 1) & (NBLK - 1))) {
            const int o = t - 1;
#pragma unroll
            for (int p = w * 6; p < w * 6 + 6; ++p) {
                const int b = p / NOUT;
                const int k = p % NOUT;
                float a = 0.f;
#pragma unroll
                for (int j = 0; j < 32; ++j) {
                    const int r = j * 64 + lane;
                    a += bf16lo(hs[b * RDIM + r]) * Wout[k * RDIM + r];
                }
#pragma unroll
                for (int off = 32; off >= 1; off >>= 1)
                    a += __shfl_xor(a, off, 64);
                if (lane == 0)
                    out[((size_t)b * TSTEPS + o) * NOUT + k] = a + bout[k];
            }
        }

        // ---- tree barrier: flags(line/group) -> l1(line) -> go2[grp] ----
        if (t < TSTEPS) {
            const unsigned tgt = (unsigned)(t + 1);
            if ((blk & 15) == 0) {
                if (w == 0) {
                    long spins = 0;               // children arrival (sole poller)
                    for (;;) {
                        unsigned vv = (lane < 16) ? sysld(&flags[grp * 16 + lane]) : tgt;
                        if (__all(vv >= tgt)) break;
                        __builtin_amdgcn_s_sleep(2);
                        if (++spins > SPIN_MAX) break;   // never hang
                    }
                    if (lane == 0) sysst(&l1[grp], tgt);
                    spins = 0;                    // all-groups arrival (16 pollers)
                    for (;;) {
                        unsigned vv = (lane < 16) ? sysld(&l1[lane]) : tgt;
                        if (__all(vv >= tgt)) break;
                        __builtin_amdgcn_s_sleep(2);
                        if (++spins > SPIN_MAX) break;
                    }
                    if (lane == 0) sysst(&go2[grp * 16], tgt);
                }
                __syncthreads();   // (#3)
            } else {
                if (tid == 0) {
                    long spins = 0;               // <=15 pollers on go2[grp]
                    while (sysld(&go2[grp * 16]) < tgt) {
                        __builtin_amdgcn_s_sleep(2);
                        if (++spins > SPIN_MAX) break;
                    }
                }
                __syncthreads();   // (#3)
            }
        }
    }
}

extern "C" void kernel_launch(void* const* d_in, const int* in_sizes, int n_in,
                              void* d_out, int out_size, void* d_ws, size_t ws_size,
                              hipStream_t stream) {
    const float* x    = (const float*)d_in[0];
    const float* Win  = (const float*)d_in[1];
    const float* W    = (const float*)d_in[2];
    const float* Wout = (const float*)d_in[3];
    const float* bout = (const float*)d_in[4];
    float* out = (float*)d_out;

    unsigned* wsu   = (unsigned*)d_ws;
    unsigned* hb0   = wsu + OFF_H0_U32;
    unsigned* hb1   = wsu + OFF_H1_U32;
    unsigned* flags = wsu + OFF_FLAGS;
    unsigned* l1    = wsu + OFF_L1;
    unsigned* go2   = wsu + OFF_GO2;

    // zero h0/h1 + all barrier state (~132 KB)
    hipMemsetAsync(d_ws, 0, (size_t)WS_USED * sizeof(unsigned), stream);

    void* args[] = {(void*)&W, (void*)&Win, (void*)&x, (void*)&Wout, (void*)&bout,
                    (void*)&hb0, (void*)&hb1, (void*)&flags, (void*)&l1,
                    (void*)&go2, (void*)&out};
    hipError_t e = hipLaunchCooperativeKernel((const void*)esn_persist,
                                              dim3(NBLK), dim3(NTHR),
                                              args, 0, stream);
    if (e != hipSuccess) {
        // Fallback: plain launch. 256 blocks co-resident on 256 CUs; bounded
        // spins guarantee no hang regardless.
        esn_persist<<<dim3(NBLK), dim3(NTHR), 0, stream>>>(
            W, Win, x, Wout, bout, hb0, hb1, flags, l1, go2, out);
    }
}

// Round 8
// 17536.263 us; speedup vs baseline: 4.1321x; 4.1321x over previous
//
#include <hip/hip_runtime.h>
#include <math.h>

// ESN reservoir, persistent kernel, round 8.
// h_t = tanh(x_t Win^T + h_{t-1} W^T); out_t = h_t Wout^T + b
//
// r5/r6 measured: barrier topology irrelevant; bottleneck = 16 MB/step UC
// h-broadcast (every CU stages ALL of h). r7's XCD relay deadlocked (scope
// semantics not provable). Round 8 removes the broadcast structurally:
//   2-D partition: block = 64 rows x 2 batches (rg = blk&31, g = blk>>5).
//   - h staged per block: 8 KB (its 2 batches only) -> 2 MB/step total UC.
//   - h[group g] produced & consumed only within group g -> 8 independent
//     32-block barriers (flags -> group aggregator -> go[g]), no global sync.
//   - W per block: rows rg*64..+64 (512 KB/step, streams from L2; with
//     round-robin placement only 2 MB W footprint per XCD -> L2-resident).
//   - out[t-1]: rotating designated block per group projects its 2 batches
//     from staged LDS h (6 dots), overlapped with barrier wait.
//   - Numerics bit-identical to r5 (same slicing/reduce) -> absmax 0.0078.
//   - All spins bounded: worst case wrong answer, never a hang.

#define RDIM   2048
#define BATCH  16
#define TSTEPS 2048
#define NIN    3
#define NOUT   3
#define NBLK   256
#define NTHR   512

#define HB_U32    ((BATCH * RDIM) / 2)      // 16384 dwords (packed bf16x2)
#define OFF_H0    0
#define OFF_H1    (HB_U32)
#define OFF_FLAGS (2 * HB_U32)              // 256 dwords: group g at [g*32..+31]
#define OFF_GO    (OFF_FLAGS + 256)         // 8 groups x 16-dword stride
#define WS_USED   (OFF_GO + 128)
#define SPIN_MAX  (1L << 20)

#define CPOL_SC0_SC1 0x11                   // UC: read at coherence point

__device__ __forceinline__ void load_lds16(const void* g, void* l) {
    __builtin_amdgcn_global_load_lds(
        (const __attribute__((address_space(1))) void*)g,
        (__attribute__((address_space(3))) void*)l, 16, 0, CPOL_SC0_SC1);
}

__device__ __forceinline__ unsigned sysld(const unsigned* p) {
    return __hip_atomic_load(p, __ATOMIC_RELAXED, __HIP_MEMORY_SCOPE_SYSTEM);
}
__device__ __forceinline__ void sysst(unsigned* p, unsigned v) {
    __hip_atomic_store(p, v, __ATOMIC_RELAXED, __HIP_MEMORY_SCOPE_SYSTEM);
}

__device__ __forceinline__ float bf16lo(unsigned u) {
    union { unsigned u; float f; } c; c.u = u << 16; return c.f;
}
__device__ __forceinline__ float bf16hi(unsigned u) {
    union { unsigned u; float f; } c; c.u = u & 0xffff0000u; return c.f;
}
__device__ __forceinline__ unsigned f2bf(float f) {
    union { float f; unsigned u; } c; c.f = f;
    unsigned r = c.u + 0x7fffu + ((c.u >> 16) & 1u);   // round-to-nearest-even
    return r >> 16;
}

extern "C" __global__ void __launch_bounds__(NTHR, 1) esn_persist(
    const float* __restrict__ W,       // [R,R]
    const float* __restrict__ Win,     // [R,3]
    const float* __restrict__ x,       // [B,T,3]
    const float* __restrict__ Wout,    // [3,R]
    const float* __restrict__ bout,    // [3]
    unsigned* hb0,                     // [B][R/2] packed bf16x2
    unsigned* hb1,
    unsigned* flags,                   // [256]
    unsigned* go,                      // [8*16]
    float* __restrict__ out)           // [B,T,3]
{
    __shared__ unsigned short hs[2 * RDIM];     // 8 KB: h for 2 batches
    __shared__ float red[8][544];               // transpose-reduce scratch
    __shared__ float hblk[64][2];               // block's 64 rows x 2 batches

    const int tid  = threadIdx.x;
    const int lane = tid & 63;
    const int w    = tid >> 6;                  // wave 0..7
    const int blk  = blockIdx.x;
    const int rg   = blk & 31;                  // row-group: rows rg*64..+64
    const int g    = blk >> 5;                  // batch-group: batches g*2..+2
    const int rbase = rg * 64 + w * 8;          // wave's 8 rows
    const int b0    = g * 2;                    // block's first batch

    const float4* W4 = (const float4*)W;

    for (int t = 0; t <= TSTEPS; ++t) {
        const unsigned* hprev = (t & 1) ? hb1 : hb0;
        unsigned*       hnext = (t & 1) ? hb0 : hb1;

        // ---- group barrier arrival check (state version t available?) ----
        if (t > 0) {
            const unsigned tgt = (unsigned)t;
            if (rg == 0) {
                if (w == 0) {
                    long spins = 0;             // sole poller of group flags
                    for (;;) {
                        unsigned vv = (lane < 32) ? sysld(&flags[g * 32 + lane]) : tgt;
                        if (__all((int)(vv >= tgt))) break;
                        __builtin_amdgcn_s_sleep(2);
                        if (++spins > SPIN_MAX) break;   // never hang
                    }
                    if (lane == 0) sysst(&go[g * 16], tgt);
                }
                __syncthreads();
            } else {
                if (tid == 0) {
                    long spins = 0;             // <=31 pollers on go[g]
                    while (sysld(&go[g * 16]) < tgt) {
                        __builtin_amdgcn_s_sleep(2);
                        if (++spins > SPIN_MAX) break;
                    }
                }
                __syncthreads();
            }
        }

        // ---- stage h[b0..b0+1][:] (8 KB) -> LDS: 512 granules, 1/thread ----
        {
            const int gran = w * 64 + lane;     // 16B granule 0..511
            load_lds16(hprev + (size_t)g * 2048 + (size_t)gran * 4,
                       hs + (size_t)(w * 64) * 8);
        }
        __syncthreads();   // staging complete (drains vmcnt)

        if (t < TSTEPS) {
            // ---- recurrence: acc[r][b] over lane's k-slice ----
            float acc[8][2];
#pragma unroll
            for (int r = 0; r < 8; ++r) { acc[r][0] = 0.f; acc[r][1] = 0.f; }

            const uint4* h16 = (const uint4*)hs;    // 256 granules per batch
#pragma unroll
            for (int c = 0; c < 4; ++c) {
                const int gr = c * 64 + lane;       // k = gr*8 .. +8
                uint4 q0 = h16[gr];                 // batch b0
                uint4 q1 = h16[256 + gr];           // batch b0+1
                float a0 = bf16lo(q0.x), a1 = bf16hi(q0.x);
                float a2 = bf16lo(q0.y), a3 = bf16hi(q0.y);
                float a4 = bf16lo(q0.z), a5 = bf16hi(q0.z);
                float a6 = bf16lo(q0.w), a7 = bf16hi(q0.w);
                float c0 = bf16lo(q1.x), c1 = bf16hi(q1.x);
                float c2 = bf16lo(q1.y), c3 = bf16hi(q1.y);
                float c4 = bf16lo(q1.z), c5 = bf16hi(q1.z);
                float c6 = bf16lo(q1.w), c7 = bf16hi(q1.w);
#pragma unroll
                for (int r = 0; r < 8; ++r) {
                    const float4* Wp = W4 + (size_t)(rbase + r) * (RDIM / 4) + gr * 2;
                    float4 w0 = Wp[0];
                    float4 w1 = Wp[1];
                    acc[r][0] += w0.x * a0 + w0.y * a1 + w0.z * a2 + w0.w * a3
                               + w1.x * a4 + w1.y * a5 + w1.z * a6 + w1.w * a7;
                    acc[r][1] += w0.x * c0 + w0.y * c1 + w0.z * c2 + w0.w * c3
                               + w1.x * c4 + w1.y * c5 + w1.z * c6 + w1.w * c7;
                }
            }

            // ---- reduce: fold 32, transpose, sum 32 partials ----
            float v[16];
#pragma unroll
            for (int i = 0; i < 16; ++i) {
                float a = acc[i >> 1][i & 1];
                v[i] = a + __shfl_xor(a, 32, 64);
            }
            if (lane < 32) {
#pragma unroll
                for (int i = 0; i < 16; ++i)
                    red[w][lane * 17 + ((i + lane) & 15)] = v[i];
            }
            __syncthreads();
            if (lane < 16) {
                float s = 0.f;
#pragma unroll
                for (int l = 0; l < 32; ++l)
                    s += red[w][l * 17 + ((lane + l) & 15)];
                const int r   = lane >> 1;          // 0..7
                const int b   = lane & 1;
                const int row = rbase + r;
                const int bg  = b0 + b;
                float pre = s;
#pragma unroll
                for (int c = 0; c < NIN; ++c)
                    pre += Win[row * NIN + c] * x[((size_t)bg * TSTEPS + t) * NIN + c];
                hblk[w * 8 + r][b] = tanhf(pre);
            }
            __syncthreads();   // hblk complete

            // ---- write h_new strips (UC): 64 packed dwords by wave 0 ----
            if (w == 0) {
                const int b = lane >> 5;            // 0..1
                const int j = lane & 31;            // dword within 64-row strip
                unsigned lo = f2bf(hblk[2 * j][b]);
                unsigned hi = f2bf(hblk[2 * j + 1][b]);
                sysst(&hnext[(size_t)(b0 + b) * (RDIM / 2) + rg * 32 + j],
                      lo | (hi << 16));
                __builtin_amdgcn_s_waitcnt(0);      // strips visible first
            }
            __syncthreads();
            if (tid == 0) sysst(&flags[g * 32 + rg], (unsigned)(t + 1));
        }

        // ---- projection of H_t for this group's 2 batches (rotating) ----
        if (t > 0 && rg == ((t - 1) & 31)) {
            const int o = t - 1;
            if (w < 6) {
                const int b = w / NOUT;             // 0..1
                const int k = w % NOUT;             // 0..2
                float a = 0.f;
#pragma unroll
                for (int j = 0; j < 32; ++j) {
                    const int r = j * 64 + lane;
                    a += bf16lo(hs[b * RDIM + r]) * Wout[k * RDIM + r];
                }
#pragma unroll
                for (int off = 32; off >= 1; off >>= 1)
                    a += __shfl_xor(a, off, 64);
                if (lane == 0)
                    out[((size_t)(b0 + b) * TSTEPS + o) * NOUT + k] = a + bout[k];
            }
        }
    }
}

extern "C" void kernel_launch(void* const* d_in, const int* in_sizes, int n_in,
                              void* d_out, int out_size, void* d_ws, size_t ws_size,
                              hipStream_t stream) {
    const float* x    = (const float*)d_in[0];
    const float* Win  = (const float*)d_in[1];
    const float* W    = (const float*)d_in[2];
    const float* Wout = (const float*)d_in[3];
    const float* bout = (const float*)d_in[4];
    float* out = (float*)d_out;

    unsigned* wsu   = (unsigned*)d_ws;
    unsigned* hb0   = wsu + OFF_H0;
    unsigned* hb1   = wsu + OFF_H1;
    unsigned* flags = wsu + OFF_FLAGS;
    unsigned* go    = wsu + OFF_GO;

    // zero h buffers + flags + go (~133 KB)
    hipMemsetAsync(d_ws, 0, (size_t)WS_USED * sizeof(unsigned), stream);

    void* args[] = {(void*)&W, (void*)&Win, (void*)&x, (void*)&Wout, (void*)&bout,
                    (void*)&hb0, (void*)&hb1, (void*)&flags, (void*)&go, (void*)&out};
    hipError_t e = hipLaunchCooperativeKernel((const void*)esn_persist,
                                              dim3(NBLK), dim3(NTHR),
                                              args, 0, stream);
    if (e != hipSuccess) {
        // Fallback: plain launch (256 blocks co-resident on 256 CUs; bounded
        // spins guarantee no hang regardless).
        esn_persist<<<dim3(NBLK), dim3(NTHR), 0, stream>>>(
            W, Win, x, Wout, bout, hb0, hb1, flags, go, out);
    }
}